// Round 4
// baseline (390.269 us; speedup 1.0000x reference)
//
#include <hip/hip_runtime.h>

#define NB 16
#define NT 4096
#define ND 512
#define NLEV 12

// ---------- exact decision path (verified rounds 2-3): f32 diffs, exact f64 sum,
// ---------- round once to f32, compare vs 1024 (== 32^2, monotone w/ sqrtf>32).
__device__ __forceinline__ bool decide_exact(const float* __restrict__ base, int row,
                                             int lane, float4 r0, float4 r1) {
    const float4* fp = (const float4*)(base + (size_t)row * ND);
    float4 y0 = fp[lane];
    float4 y1 = fp[lane + 64];
    float d;
    double sd;
    d = r0.x - y0.x; sd  = (double)d * d;
    d = r0.y - y0.y; sd += (double)d * d;
    d = r0.z - y0.z; sd += (double)d * d;
    d = r0.w - y0.w; sd += (double)d * d;
    d = r1.x - y1.x; sd += (double)d * d;
    d = r1.y - y1.y; sd += (double)d * d;
    d = r1.z - y1.z; sd += (double)d * d;
    d = r1.w - y1.w; sd += (double)d * d;
    #pragma unroll
    for (int off = 32; off >= 1; off >>= 1) sd += __shfl_xor(sd, off, 64);
    return ((float)sd > 1024.0f);
}

#define DIST8_F32(sout, y0, y1)                                   \
    {                                                             \
        float d_;                                                 \
        d_ = r0.x - (y0).x; sout = d_ * d_;                       \
        d_ = r0.y - (y0).y; sout = fmaf(d_, d_, sout);            \
        d_ = r0.z - (y0).z; sout = fmaf(d_, d_, sout);            \
        d_ = r0.w - (y0).w; sout = fmaf(d_, d_, sout);            \
        d_ = r1.x - (y1).x; sout = fmaf(d_, d_, sout);            \
        d_ = r1.y - (y1).y; sout = fmaf(d_, d_, sout);            \
        d_ = r1.z - (y1).z; sout = fmaf(d_, d_, sout);            \
        d_ = r1.w - (y1).w; sout = fmaf(d_, d_, sout);            \
    }

__device__ __forceinline__ bool screen1(float sk, const float* __restrict__ base,
                                        int row, int lane, float4 r0, float4 r1) {
    if (sk > 1024.25f) return true;
    if (sk < 1023.75f) return false;
    return decide_exact(base, row, lane, r0, r1);
}

// ---------------- Kernel A v4: 16 j per wave, window-4, shuffle-free ----------------
// lane = js*4+p computes the FULL 512-dim distance d^2(j0+js, j0+js+1+p) serially
// in registers (f32, serial-sum err << 0.25 margin). No crosslane reduction at all.
__global__ __launch_bounds__(256) void kA_next(const float* __restrict__ in,
                                               int* __restrict__ nxt,
                                               int2* __restrict__ list,
                                               int* __restrict__ cnt) {
    int wave = blockIdx.x * 4 + (threadIdx.x >> 6);
    int lane = threadIdx.x & 63;
    int j0 = wave * 16;                  // 16 j per wave, same batch (16 | 4096)
    int b  = j0 >> 12;
    int js = lane >> 2;
    int p  = lane & 3;
    int j  = (j0 & (NT - 1)) + js;
    int ri = j + 1 + p;
    bool valid = ri < NT;
    int rc = valid ? ri : j;             // safe in-bounds address for invalid lanes

    const float* base = in + (size_t)b * NT * ND;
    const float4* rp = (const float4*)(base + (size_t)j  * ND);
    const float4* xp = (const float4*)(base + (size_t)rc * ND);

    float s = 0.f;
    #pragma unroll 8
    for (int c = 0; c < 128; ++c) {
        float4 a = rp[c];
        float4 x = xp[c];
        float d;
        d = a.x - x.x; s = fmaf(d, d, s);
        d = a.y - x.y; s = fmaf(d, d, s);
        d = a.z - x.z; s = fmaf(d, d, s);
        d = a.w - x.w; s = fmaf(d, d, s);
    }

    unsigned long long yes = __ballot(valid && (s > 1024.25f));
    unsigned long long amb = __ballot(valid && (s > 1023.75f) && (s <= 1024.25f));

    if (p == 0) {
        int bj = b * NT + j;
        unsigned ny = (unsigned)(yes >> (js * 4)) & 0xFu;
        unsigned na = (unsigned)(amb >> (js * 4)) & 0xFu;
        int ry = ny ? (__ffs(ny) - 1) : 4;
        int ra = na ? (__ffs(na) - 1) : 4;
        if (ra < ry) {                              // ambiguous first -> exact path
            int idx = atomicAdd(cnt, 1);
            list[idx] = make_int2(bj, j + 1 + ra);
        } else if (ry < 4) {
            nxt[bj] = j + 1 + ry;
        } else if (j <= NT - 6) {                   // window exhausted, more rows exist
            int idx = atomicAdd(cnt, 1);
            list[idx] = make_int2(bj, j + 5);
        } else {
            nxt[bj] = NT;                           // probed through NT-1: no exceed
        }
    }
}

// ---------------- Kernel A2: resolve stragglers (wave per entry, serial probe) ------
__global__ __launch_bounds__(256) void kA2_tail(const float* __restrict__ in,
                                                const int2* __restrict__ list,
                                                const int* __restrict__ cnt,
                                                int* __restrict__ nxt) {
    int wave = blockIdx.x * 4 + (threadIdx.x >> 6);
    int lane = threadIdx.x & 63;
    int n = *cnt;
    for (int e = wave; e < n; e += 2048) {
        int2 ent = list[e];
        int bj = ent.x;
        int b = bj >> 12, j = bj & (NT - 1);
        const float* base = in + (size_t)b * NT * ND;
        const float4* repp = (const float4*)(base + (size_t)j * ND);
        float4 r0 = repp[lane];
        float4 r1 = repp[lane + 64];
        int result = NT;
        int i = ent.y;
        while (i < NT) {
            int row0 = i;
            int row1 = (i + 1 < NT) ? i + 1 : NT - 1;
            int row2 = (i + 2 < NT) ? i + 2 : NT - 1;
            int row3 = (i + 3 < NT) ? i + 3 : NT - 1;
            const float4* f0 = (const float4*)(base + (size_t)row0 * ND);
            const float4* f1 = (const float4*)(base + (size_t)row1 * ND);
            const float4* f2 = (const float4*)(base + (size_t)row2 * ND);
            const float4* f3 = (const float4*)(base + (size_t)row3 * ND);
            float4 a0 = f0[lane], b0 = f0[lane + 64];
            float4 a1 = f1[lane], b1 = f1[lane + 64];
            float4 a2 = f2[lane], b2 = f2[lane + 64];
            float4 a3 = f3[lane], b3 = f3[lane + 64];
            float s0, s1, s2, s3;
            DIST8_F32(s0, a0, b0);
            DIST8_F32(s1, a1, b1);
            DIST8_F32(s2, a2, b2);
            DIST8_F32(s3, a3, b3);
            #pragma unroll
            for (int off = 32; off >= 1; off >>= 1) {
                s0 += __shfl_xor(s0, off, 64);
                s1 += __shfl_xor(s1, off, 64);
                s2 += __shfl_xor(s2, off, 64);
                s3 += __shfl_xor(s3, off, 64);
            }
            int nv = NT - i;
            int found = -1;
            if (screen1(s0, base, row0, lane, r0, r1)) found = i;
            else if (nv > 1 && screen1(s1, base, row1, lane, r0, r1)) found = i + 1;
            else if (nv > 2 && screen1(s2, base, row2, lane, r0, r1)) found = i + 2;
            else if (nv > 3 && screen1(s3, base, row3, lane, r0, r1)) found = i + 3;
            if (found >= 0) { result = found; break; }
            i += 4;
        }
        if (lane == 0) nxt[bj] = result;
    }
}

// ---------------- kChain: doubling + reach bitmap + ranks, one block per batch ------
__global__ __launch_bounds__(1024) void kChain(const int* __restrict__ nxt,
                                               int* __restrict__ start,
                                               int* __restrict__ nseg,
                                               float* __restrict__ out_tail) {
    __shared__ unsigned short h[NT + 1];
    __shared__ unsigned short h2[NT + 1];
    __shared__ unsigned reach[NT / 32];
    __shared__ unsigned pref[NT / 32];
    __shared__ unsigned wsum[NT / 32];
    int b = blockIdx.x;
    int t = threadIdx.x;
    for (int j = t; j <= NT; j += 1024)
        h[j] = (j < NT) ? (unsigned short)nxt[b * NT + j] : (unsigned short)NT;
    for (int w = t; w < NT / 32; w += 1024) reach[w] = 0;
    __syncthreads();
    if (t == 0) reach[0] = 1u;
    __syncthreads();
    for (int k = 0; k < NLEV; ++k) {
        // R |= f^(2^k)(R)  (snapshot-or-better; extra closure applications are safe)
        if (t < NT / 32) {
            unsigned m = reach[t];
            while (m) {
                int bit = __ffs(m) - 1; m &= m - 1;
                int d = h[t * 32 + bit];
                if (d < NT) atomicOr(&reach[d >> 5], 1u << (d & 31));
            }
        }
        __syncthreads();
        for (int j = t; j <= NT; j += 1024) h2[j] = h[h[j]];
        __syncthreads();
        for (int j = t; j <= NT; j += 1024) h[j] = h2[j];
        __syncthreads();
    }
    if (t < NT / 32) { wsum[t] = __popc(reach[t]); pref[t] = wsum[t]; }
    __syncthreads();
    for (int off = 1; off < NT / 32; off <<= 1) {
        unsigned v = 0;
        if (t < NT / 32 && t >= off) v = pref[t - off];
        __syncthreads();
        if (t < NT / 32) pref[t] += v;
        __syncthreads();
    }
    int n = pref[NT / 32 - 1];
    for (int j = t; j < NT; j += 1024) {
        unsigned w = reach[j >> 5];
        if (w & (1u << (j & 31))) {
            int r = (int)(pref[j >> 5] - __popc(w) + __popc(w & ((1u << (j & 31)) - 1)));
            start[b * NT + r] = j;
        }
    }
    if (t == 0) { nseg[b] = n; out_tail[b] = (float)n; }
}

// ---------------- Kernel D: means + zeros, ONE wave per output row ------------------
__global__ __launch_bounds__(256) void kD_means(const float* __restrict__ in,
                                                const int* __restrict__ nxt,
                                                const int* __restrict__ start,
                                                const int* __restrict__ nseg,
                                                float* __restrict__ out) {
    int wave = blockIdx.x * 4 + (threadIdx.x >> 6);   // 0..65535 = (b, r)
    int lane = threadIdx.x & 63;
    int b = wave >> 12;
    int r = wave & (NT - 1);
    float4 acc0 = make_float4(0.f, 0.f, 0.f, 0.f);
    float4 acc1 = make_float4(0.f, 0.f, 0.f, 0.f);
    int n = nseg[b];
    if (r < n) {
        int s = start[b * NT + r];
        int e = nxt[b * NT + s];
        const float4* base = (const float4*)(in + (size_t)(b * NT + s) * ND);
        int cnt = e - s;
        int f = 0;
        for (; f + 2 <= cnt; f += 2) {
            float4 v0 = base[(size_t)f * (ND / 4) + lane];
            float4 v1 = base[(size_t)f * (ND / 4) + lane + 64];
            float4 w0 = base[(size_t)(f + 1) * (ND / 4) + lane];
            float4 w1 = base[(size_t)(f + 1) * (ND / 4) + lane + 64];
            acc0.x += v0.x + w0.x; acc0.y += v0.y + w0.y;
            acc0.z += v0.z + w0.z; acc0.w += v0.w + w0.w;
            acc1.x += v1.x + w1.x; acc1.y += v1.y + w1.y;
            acc1.z += v1.z + w1.z; acc1.w += v1.w + w1.w;
        }
        if (f < cnt) {
            float4 v0 = base[(size_t)f * (ND / 4) + lane];
            float4 v1 = base[(size_t)f * (ND / 4) + lane + 64];
            acc0.x += v0.x; acc0.y += v0.y; acc0.z += v0.z; acc0.w += v0.w;
            acc1.x += v1.x; acc1.y += v1.y; acc1.z += v1.z; acc1.w += v1.w;
        }
        float c = (float)cnt;
        acc0.x /= c; acc0.y /= c; acc0.z /= c; acc0.w /= c;
        acc1.x /= c; acc1.y /= c; acc1.z /= c; acc1.w /= c;
    }
    float4* orow = (float4*)(out + (size_t)(b * NT + r) * ND);
    orow[lane]      = acc0;
    orow[lane + 64] = acc1;
}

extern "C" void kernel_launch(void* const* d_in, const int* in_sizes, int n_in,
                              void* d_out, int out_size, void* d_ws, size_t ws_size,
                              hipStream_t stream) {
    const float* in = (const float*)d_in[0];
    float* out = (float*)d_out;
    char* ws = (char*)d_ws;

    int*  nxt   = (int*)(ws + 0);           // 256 KiB
    int*  start = (int*)(ws + 262144);      // 256 KiB
    int*  nseg  = (int*)(ws + 524288);      // 64 B
    int*  cnt   = (int*)(ws + 524352);      // 64 B
    int2* list  = (int2*)(ws + 524416);     // 512 KiB (worst case 65536 entries)

    hipMemsetAsync(cnt, 0, 4, stream);

    kA_next <<<1024,  256,  0, stream>>>(in, nxt, list, cnt);
    kA2_tail<<<512,   256,  0, stream>>>(in, list, cnt, nxt);
    kChain  <<<NB,    1024, 0, stream>>>(nxt, start, nseg,
                                         out + (size_t)NB * NT * ND);
    kD_means<<<16384, 256,  0, stream>>>(in, nxt, start, nseg, out);
}

// Round 5
// 317.523 us; speedup vs baseline: 1.2291x; 1.2291x over previous
//
#include <hip/hip_runtime.h>

#define NB 16
#define NT 4096
#define ND 512
#define NLEV 12

// ---------- exact decision path (verified rounds 2-4): f32 diffs, exact f64 sum,
// ---------- round once to f32, compare vs 1024 (== 32^2, monotone w/ sqrtf>32).
__device__ __forceinline__ bool decide_exact(const float* __restrict__ base, int row,
                                             int lane, float4 r0, float4 r1) {
    const float4* fp = (const float4*)(base + (size_t)row * ND);
    float4 y0 = fp[lane];
    float4 y1 = fp[lane + 64];
    float d;
    double sd;
    d = r0.x - y0.x; sd  = (double)d * d;
    d = r0.y - y0.y; sd += (double)d * d;
    d = r0.z - y0.z; sd += (double)d * d;
    d = r0.w - y0.w; sd += (double)d * d;
    d = r1.x - y1.x; sd += (double)d * d;
    d = r1.y - y1.y; sd += (double)d * d;
    d = r1.z - y1.z; sd += (double)d * d;
    d = r1.w - y1.w; sd += (double)d * d;
    #pragma unroll
    for (int off = 32; off >= 1; off >>= 1) sd += __shfl_xor(sd, off, 64);
    return ((float)sd > 1024.0f);
}

// ---------------- Kernel A v5: wave per j, 16-lane group per probe ----------------
// rep row resident in 32 VGPRs (8 float4 chunks per lane, striped by lane&15).
// 4 probes per batch; only 4 shuffle steps per batch; coalesced 256B/group loads.
__global__ __launch_bounds__(256) void kA_next(const float* __restrict__ in,
                                               int* __restrict__ nxt) {
    int wave = blockIdx.x * 4 + (threadIdx.x >> 6);   // 0..65535 = (b, j)
    int lane = threadIdx.x & 63;
    int b = wave >> 12;
    int j = wave & (NT - 1);
    int g = lane >> 4;    // probe group 0..3
    int q = lane & 15;    // lane within group

    const float* base = in + (size_t)b * NT * ND;
    const float4* jrow = (const float4*)(base + (size_t)j * ND);
    float4 rep[8];
    #pragma unroll
    for (int k = 0; k < 8; ++k) rep[k] = jrow[q + 16 * k];

    int result = NT;
    int i = j + 1;
    while (i < NT) {
        int row = i + g;
        bool valid = row < NT;
        int rc = valid ? row : NT - 1;
        const float4* pr = (const float4*)(base + (size_t)rc * ND);
        float s = 0.f;
        #pragma unroll
        for (int k = 0; k < 8; ++k) {
            float4 x = pr[q + 16 * k];
            float d;
            d = rep[k].x - x.x; s = fmaf(d, d, s);
            d = rep[k].y - x.y; s = fmaf(d, d, s);
            d = rep[k].z - x.z; s = fmaf(d, d, s);
            d = rep[k].w - x.w; s = fmaf(d, d, s);
        }
        // 16-lane group reduction (stays within group: offsets < 16)
        s += __shfl_xor(s, 1, 64);
        s += __shfl_xor(s, 2, 64);
        s += __shfl_xor(s, 4, 64);
        s += __shfl_xor(s, 8, 64);

        unsigned long long ym = __ballot(q == 0 && valid && s > 1024.25f);
        unsigned long long am = __ballot(q == 0 && valid && s > 1023.75f && s <= 1024.25f);
        // group verdict bits live at lanes 0,16,32,48 -> compact to 4 bits
        unsigned vy = (unsigned)((ym & 1ull) | ((ym >> 15) & 2ull) |
                                 ((ym >> 30) & 4ull) | ((ym >> 45) & 8ull));
        unsigned va = (unsigned)((am & 1ull) | ((am >> 15) & 2ull) |
                                 ((am >> 30) & 4ull) | ((am >> 45) & 8ull));
        int found = -1;
        for (;;) {   // wave-uniform resolve in ascending probe order
            int gy = vy ? (__ffs(vy) - 1) : 4;
            int ga = va ? (__ffs(va) - 1) : 4;
            if (ga < gy) {
                float4 r0 = jrow[lane];        // L1-hot reload, rare path
                float4 r1 = jrow[lane + 64];
                if (decide_exact(base, i + ga, lane, r0, r1)) { found = i + ga; break; }
                va &= va - 1;
            } else {
                if (gy < 4) found = i + gy;
                break;
            }
        }
        if (found >= 0) { result = found; break; }
        i += 4;
    }
    if (lane == 0) nxt[b * NT + j] = result;
}

// ---------------- kChain: doubling + reach bitmap + ranks (verified r4) -----------
__global__ __launch_bounds__(1024) void kChain(const int* __restrict__ nxt,
                                               int* __restrict__ start,
                                               int* __restrict__ nseg,
                                               float* __restrict__ out_tail) {
    __shared__ unsigned short h[NT + 1];
    __shared__ unsigned short h2[NT + 1];
    __shared__ unsigned reach[NT / 32];
    __shared__ unsigned pref[NT / 32];
    __shared__ unsigned wsum[NT / 32];
    int b = blockIdx.x;
    int t = threadIdx.x;
    for (int j = t; j <= NT; j += 1024)
        h[j] = (j < NT) ? (unsigned short)nxt[b * NT + j] : (unsigned short)NT;
    for (int w = t; w < NT / 32; w += 1024) reach[w] = 0;
    __syncthreads();
    if (t == 0) reach[0] = 1u;
    __syncthreads();
    for (int k = 0; k < NLEV; ++k) {
        if (t < NT / 32) {
            unsigned m = reach[t];
            while (m) {
                int bit = __ffs(m) - 1; m &= m - 1;
                int d = h[t * 32 + bit];
                if (d < NT) atomicOr(&reach[d >> 5], 1u << (d & 31));
            }
        }
        __syncthreads();
        for (int j = t; j <= NT; j += 1024) h2[j] = h[h[j]];
        __syncthreads();
        for (int j = t; j <= NT; j += 1024) h[j] = h2[j];
        __syncthreads();
    }
    if (t < NT / 32) { wsum[t] = __popc(reach[t]); pref[t] = wsum[t]; }
    __syncthreads();
    for (int off = 1; off < NT / 32; off <<= 1) {
        unsigned v = 0;
        if (t < NT / 32 && t >= off) v = pref[t - off];
        __syncthreads();
        if (t < NT / 32) pref[t] += v;
        __syncthreads();
    }
    int n = pref[NT / 32 - 1];
    for (int j = t; j < NT; j += 1024) {
        unsigned w = reach[j >> 5];
        if (w & (1u << (j & 31))) {
            int r = (int)(pref[j >> 5] - __popc(w) + __popc(w & ((1u << (j & 31)) - 1)));
            start[b * NT + r] = j;
        }
    }
    if (t == 0) { nseg[b] = n; out_tail[b] = (float)n; }
}

// ---------------- Kernel D: means + zeros, one wave per output row (verified r4) --
__global__ __launch_bounds__(256) void kD_means(const float* __restrict__ in,
                                                const int* __restrict__ nxt,
                                                const int* __restrict__ start,
                                                const int* __restrict__ nseg,
                                                float* __restrict__ out) {
    int wave = blockIdx.x * 4 + (threadIdx.x >> 6);   // 0..65535 = (b, r)
    int lane = threadIdx.x & 63;
    int b = wave >> 12;
    int r = wave & (NT - 1);
    float4 acc0 = make_float4(0.f, 0.f, 0.f, 0.f);
    float4 acc1 = make_float4(0.f, 0.f, 0.f, 0.f);
    int n = nseg[b];
    if (r < n) {
        int s = start[b * NT + r];
        int e = nxt[b * NT + s];
        const float4* base = (const float4*)(in + (size_t)(b * NT + s) * ND);
        int cnt = e - s;
        int f = 0;
        for (; f + 2 <= cnt; f += 2) {
            float4 v0 = base[(size_t)f * (ND / 4) + lane];
            float4 v1 = base[(size_t)f * (ND / 4) + lane + 64];
            float4 w0 = base[(size_t)(f + 1) * (ND / 4) + lane];
            float4 w1 = base[(size_t)(f + 1) * (ND / 4) + lane + 64];
            acc0.x += v0.x + w0.x; acc0.y += v0.y + w0.y;
            acc0.z += v0.z + w0.z; acc0.w += v0.w + w0.w;
            acc1.x += v1.x + w1.x; acc1.y += v1.y + w1.y;
            acc1.z += v1.z + w1.z; acc1.w += v1.w + w1.w;
        }
        if (f < cnt) {
            float4 v0 = base[(size_t)f * (ND / 4) + lane];
            float4 v1 = base[(size_t)f * (ND / 4) + lane + 64];
            acc0.x += v0.x; acc0.y += v0.y; acc0.z += v0.z; acc0.w += v0.w;
            acc1.x += v1.x; acc1.y += v1.y; acc1.z += v1.z; acc1.w += v1.w;
        }
        float c = (float)cnt;
        acc0.x /= c; acc0.y /= c; acc0.z /= c; acc0.w /= c;
        acc1.x /= c; acc1.y /= c; acc1.z /= c; acc1.w /= c;
    }
    float4* orow = (float4*)(out + (size_t)(b * NT + r) * ND);
    orow[lane]      = acc0;
    orow[lane + 64] = acc1;
}

extern "C" void kernel_launch(void* const* d_in, const int* in_sizes, int n_in,
                              void* d_out, int out_size, void* d_ws, size_t ws_size,
                              hipStream_t stream) {
    const float* in = (const float*)d_in[0];
    float* out = (float*)d_out;
    char* ws = (char*)d_ws;

    int* nxt   = (int*)(ws + 0);           // 256 KiB
    int* start = (int*)(ws + 262144);      // 256 KiB
    int* nseg  = (int*)(ws + 524288);      // 64 B

    kA_next <<<16384, 256,  0, stream>>>(in, nxt);
    kChain  <<<NB,    1024, 0, stream>>>(nxt, start, nseg,
                                         out + (size_t)NB * NT * ND);
    kD_means<<<16384, 256,  0, stream>>>(in, nxt, start, nseg, out);
}